// Round 2
// baseline (3990.796 us; speedup 1.0000x reference)
//
#include <hip/hip_runtime.h>
#include <math.h>

#define L_SEQ 1024
#define WIN   32
#define CDIM  144
#define NW    993            // (1024-32)/1 + 1
#define HDIM  512
#define RDIM  256
#define M_ROWS (NW*CDIM)     // 142992
#define TILE_M 16
#define SLOPE 0.1

__device__ __forceinline__ double dlrelu(double x){ return x >= 0.0 ? x : SLOPE*x; }

// ---------------- prologue: axis-angle -> 6D (fp64 math) ----------------
__global__ void k_prep(const float* __restrict__ dp, float* __restrict__ d6){
  int idx = blockIdx.x*256 + threadIdx.x;
  if (idx >= L_SEQ*24) return;
  int l = idx / 24, j = idx % 24;
  const float* a = dp + l*72 + j*3;
  double x = (double)a[0], y = (double)a[1], z = (double)a[2];
  double ang = sqrt(x*x + y*y + z*z);
  double inv = 1.0 / fmax(ang, 1e-8);
  double ax = x*inv, ay = y*inv, az = z*inv;
  double s = sin(ang), c = cos(ang), C = 1.0 - c;
  float* o = d6 + l*CDIM + j*6;
  o[0] = (float)(c + ax*ax*C);
  o[1] = (float)(ax*ay*C - az*s);
  o[2] = (float)(ax*az*C + ay*s);
  o[3] = (float)(ay*ax*C + az*s);
  o[4] = (float)(c + ay*ay*C);
  o[5] = (float)(ay*az*C - ax*s);
}

// ---------------- weight transpose ----------------
__global__ void k_transpose(const float* __restrict__ src, float* __restrict__ dst,
                            int R, int C){
  int idx = blockIdx.x*256 + threadIdx.x;
  if (idx >= R*C) return;
  int r = idx / C, c = idx % C;
  dst[c*R + r] = src[idx];
}

// ---------------- fused MLP ----------------
// src layout in LDS: S[k*16 + row]  (k = input dim, row = 0..15), fp32
// Wt layout in ws:   Wt[k*JD + j]   (pre-transposed), fp32
// Accumulation: fp64 (v_fma_f64) to stay below jax-fp32's own rounding noise.
template<int KD, int JD, bool RES>
__device__ __forceinline__ void layer(const float* S, float* D,
                                      const float* __restrict__ Wt,
                                      const float* __restrict__ bias){
  const int rg = threadIdx.x >> 7;     // 0..1 (row half)
  const int cg = threadIdx.x & 127;    // 0..127 (col group)
  constexpr int JT = JD / 128;         // 2 (JD=256) or 4 (JD=512)
  const int rbase = rg * 8;
  double acc[8][JT];
  #pragma unroll
  for (int i = 0; i < 8; ++i)
    #pragma unroll
    for (int u = 0; u < JT; ++u) acc[i][u] = 0.0;

  #pragma unroll 2
  for (int k = 0; k < KD; ++k){
    // wave-uniform LDS broadcast reads (all lanes same address)
    float4 a0 = *(const float4*)(S + k*16 + rbase);
    float4 a1 = *(const float4*)(S + k*16 + rbase + 4);
    double w[JT];
    #pragma unroll
    for (int u = 0; u < JT; ++u) w[u] = (double)Wt[k*JD + cg + 128*u]; // coalesced
    #pragma unroll
    for (int u = 0; u < JT; ++u){
      acc[0][u] = fma((double)a0.x, w[u], acc[0][u]);
      acc[1][u] = fma((double)a0.y, w[u], acc[1][u]);
      acc[2][u] = fma((double)a0.z, w[u], acc[2][u]);
      acc[3][u] = fma((double)a0.w, w[u], acc[3][u]);
      acc[4][u] = fma((double)a1.x, w[u], acc[4][u]);
      acc[5][u] = fma((double)a1.y, w[u], acc[5][u]);
      acc[6][u] = fma((double)a1.z, w[u], acc[6][u]);
      acc[7][u] = fma((double)a1.w, w[u], acc[7][u]);
    }
  }
  #pragma unroll
  for (int u = 0; u < JT; ++u){
    int j = cg + 128*u;
    double b = (double)bias[j];
    float v0 = (float)dlrelu(acc[0][u]+b), v1 = (float)dlrelu(acc[1][u]+b);
    float v2 = (float)dlrelu(acc[2][u]+b), v3 = (float)dlrelu(acc[3][u]+b);
    float v4 = (float)dlrelu(acc[4][u]+b), v5 = (float)dlrelu(acc[5][u]+b);
    float v6 = (float)dlrelu(acc[6][u]+b), v7 = (float)dlrelu(acc[7][u]+b);
    float* dp0 = D + j*16 + rbase;
    if (RES){
      float4 o0 = *(float4*)dp0;     float4 o1 = *(float4*)(dp0+4);
      o0.x += v0; o0.y += v1; o0.z += v2; o0.w += v3;
      o1.x += v4; o1.y += v5; o1.z += v6; o1.w += v7;
      *(float4*)dp0 = o0; *(float4*)(dp0+4) = o1;
    } else {
      *(float4*)dp0     = make_float4(v0,v1,v2,v3);
      *(float4*)(dp0+4) = make_float4(v4,v5,v6,v7);
    }
  }
}

__global__ __launch_bounds__(256) void k_mlp(
    const float* __restrict__ d6,
    const float* __restrict__ w_inT, const float* __restrict__ b_in,
    const float* __restrict__ w1aT, const float* __restrict__ b1a,
    const float* __restrict__ w1bT, const float* __restrict__ b1b,
    const float* __restrict__ w2aT, const float* __restrict__ b2a,
    const float* __restrict__ w2bT, const float* __restrict__ b2b,
    const float* __restrict__ w_outT, const float* __restrict__ b_out,
    float* __restrict__ y)
{
  __shared__ __align__(16) float xb[16][33];       // padded: conflict-free
  __shared__ __align__(16) float hb[HDIM*16];      // h tile, [k][row]
  __shared__ __align__(16) float rb[RDIM*16];      // r tile, [k][row]
  const int tid = threadIdx.x;
  const int m0  = blockIdx.x * TILE_M;

  // gather input windows: xb[r][t] = d6[(n+t)*144 + c]
  for (int idx = tid; idx < TILE_M*WIN; idx += 256){
    int r = idx & 15, t = idx >> 4;
    int m = m0 + r;
    int n = m / CDIM, c = m % CDIM;
    xb[r][t] = d6[(n+t)*CDIM + c];
  }
  __syncthreads();

  // ---- layer in: 32 -> 512 ----
  {
    const int j0 = tid, j1 = tid + 256;
    double acc0[16], acc1[16];
    #pragma unroll
    for (int r = 0; r < 16; ++r){ acc0[r]=0.0; acc1[r]=0.0; }
    #pragma unroll 2
    for (int t = 0; t < WIN; ++t){
      double w0 = (double)w_inT[t*HDIM + j0];
      double w1 = (double)w_inT[t*HDIM + j1];
      #pragma unroll
      for (int r = 0; r < 16; ++r){
        double xv = (double)xb[r][t];             // broadcast
        acc0[r] = fma(xv, w0, acc0[r]);
        acc1[r] = fma(xv, w1, acc1[r]);
      }
    }
    double bb0 = (double)b_in[j0], bb1 = (double)b_in[j1];
    #pragma unroll
    for (int r = 0; r < 16; r += 4){
      *(float4*)(hb + j0*16 + r) = make_float4(
        (float)dlrelu(acc0[r]+bb0),   (float)dlrelu(acc0[r+1]+bb0),
        (float)dlrelu(acc0[r+2]+bb0), (float)dlrelu(acc0[r+3]+bb0));
      *(float4*)(hb + j1*16 + r) = make_float4(
        (float)dlrelu(acc1[r]+bb1),   (float)dlrelu(acc1[r+1]+bb1),
        (float)dlrelu(acc1[r+2]+bb1), (float)dlrelu(acc1[r+3]+bb1));
    }
  }
  __syncthreads();

  layer<HDIM, RDIM, false>(hb, rb, w1aT, b1a);  __syncthreads();
  layer<RDIM, HDIM, true >(rb, hb, w1bT, b1b);  __syncthreads();
  layer<HDIM, RDIM, false>(hb, rb, w2aT, b2a);  __syncthreads();
  layer<RDIM, HDIM, true >(rb, hb, w2bT, b2b);  __syncthreads();

  // ---- layer out: 512 -> 32, write y[t_local][n][c] ----
  {
    const int r  = tid & 15;
    const int th = tid >> 4;           // 0..15
    const int t0 = th, t1 = th + 16;
    double o0 = 0.0, o1 = 0.0;
    #pragma unroll 2
    for (int k = 0; k < HDIM; ++k){
      double hv = (double)hb[k*16 + r];
      o0 = fma(hv, (double)w_outT[k*32 + t0], o0);
      o1 = fma(hv, (double)w_outT[k*32 + t1], o1);
    }
    int m = m0 + r;
    int n = m / CDIM, c = m % CDIM;
    y[t0*(NW*CDIM) + n*CDIM + c] = (float)(o0 + (double)b_out[t0]);
    y[t1*(NW*CDIM) + n*CDIM + c] = (float)(o1 + (double)b_out[t1]);
  }
}

// ---------------- overlap-average scatter (fp64 sum) ----------------
__global__ void k_scatter(const float* __restrict__ y, float* __restrict__ seq){
  int idx = blockIdx.x*256 + threadIdx.x;
  if (idx >= L_SEQ*CDIM) return;
  int t = idx / CDIM, c = idx % CDIM;
  int nlo = t - (WIN-1); if (nlo < 0) nlo = 0;
  int nhi = t; if (nhi > NW-1) nhi = NW-1;
  double s = 0.0;
  for (int n = nlo; n <= nhi; ++n)
    s += (double)y[(t-n)*(NW*CDIM) + n*CDIM + c];
  seq[idx] = (float)(s / (double)(nhi - nlo + 1));
}

// ---------------- epilogue: 6D -> axis-angle (fp64 math) ----------------
__global__ void k_post(const float* __restrict__ seq, float* __restrict__ out){
  int idx = blockIdx.x*256 + threadIdx.x;
  if (idx >= L_SEQ*24) return;
  int t = idx / 24, j = idx % 24;
  const float* s = seq + t*CDIM + j*6;
  double a1x=(double)s[0], a1y=(double)s[1], a1z=(double)s[2];
  double a2x=(double)s[3], a2y=(double)s[4], a2z=(double)s[5];
  double n1 = sqrt(a1x*a1x + a1y*a1y + a1z*a1z);
  double i1 = 1.0 / fmax(n1, 1e-8);
  double b1x=a1x*i1, b1y=a1y*i1, b1z=a1z*i1;
  double d  = b1x*a2x + b1y*a2y + b1z*a2z;
  double px = a2x - d*b1x, py = a2y - d*b1y, pz = a2z - d*b1z;
  double n2 = sqrt(px*px + py*py + pz*pz);
  double i2 = 1.0 / fmax(n2, 1e-8);
  double b2x=px*i2, b2y=py*i2, b2z=pz*i2;
  double b3x = b1y*b2z - b1z*b2y;
  double b3y = b1z*b2x - b1x*b2z;
  double b3z = b1x*b2y - b1y*b2x;
  double tr = b1x + b2y + b3z;
  double cs = fmin(fmax((tr-1.0)*0.5, -1.0+1e-6), 1.0-1e-6);
  double ang = acos(cs);
  double sn  = sqrt(fmax(1.0 - cs*cs, 1e-12));
  double vx = b3y - b2z, vy = b1z - b3x, vz = b2x - b1y;
  double f = ang / (2.0 * sn);
  float* o = out + t*72 + j*3;
  o[0] = (float)(vx*f); o[1] = (float)(vy*f); o[2] = (float)(vz*f);
}

// ---------------- launcher ----------------
extern "C" void kernel_launch(void* const* d_in, const int* in_sizes, int n_in,
                              void* d_out, int out_size, void* d_ws, size_t ws_size,
                              hipStream_t stream) {
  const float* dp    = (const float*)d_in[0];
  const float* w_in  = (const float*)d_in[1];
  const float* b_in  = (const float*)d_in[2];
  const float* w1a   = (const float*)d_in[3];
  const float* b1a   = (const float*)d_in[4];
  const float* w1b   = (const float*)d_in[5];
  const float* b1b   = (const float*)d_in[6];
  const float* w2a   = (const float*)d_in[7];
  const float* b2a   = (const float*)d_in[8];
  const float* w2b   = (const float*)d_in[9];
  const float* b2b   = (const float*)d_in[10];
  const float* w_out = (const float*)d_in[11];
  const float* b_out = (const float*)d_in[12];
  float* out = (float*)d_out;

  float* d6    = (float*)d_ws;             // 1024*144            = 147456
  float* winT  = d6    + 147456;           // 32*512              = 16384
  float* w1aT  = winT  + 16384;            // 512*256             = 131072
  float* w1bT  = w1aT  + 131072;           // 256*512             = 131072
  float* w2aT  = w1bT  + 131072;
  float* w2bT  = w2aT  + 131072;
  float* woutT = w2bT  + 131072;           // 512*32              = 16384
  float* ybuf  = woutT + 16384;            // 32*993*144          = 4575744
  float* seq   = ybuf  + (size_t)WIN*NW*CDIM; // 147456

  k_prep<<<(L_SEQ*24 + 255)/256, 256, 0, stream>>>(dp, d6);

  k_transpose<<<(512*32  + 255)/256, 256, 0, stream>>>(w_in,  winT,  512, 32);
  k_transpose<<<(256*512 + 255)/256, 256, 0, stream>>>(w1a,   w1aT,  256, 512);
  k_transpose<<<(512*256 + 255)/256, 256, 0, stream>>>(w1b,   w1bT,  512, 256);
  k_transpose<<<(256*512 + 255)/256, 256, 0, stream>>>(w2a,   w2aT,  256, 512);
  k_transpose<<<(512*256 + 255)/256, 256, 0, stream>>>(w2b,   w2bT,  512, 256);
  k_transpose<<<(32*512  + 255)/256, 256, 0, stream>>>(w_out, woutT, 32, 512);

  k_mlp<<<M_ROWS/TILE_M, 256, 0, stream>>>(d6,
      winT, b_in, w1aT, b1a, w1bT, b1b, w2aT, b2a, w2bT, b2b, woutT, b_out,
      ybuf);

  k_scatter<<<(L_SEQ*CDIM + 255)/256, 256, 0, stream>>>(ybuf, seq);
  k_post<<<(L_SEQ*24 + 255)/256, 256, 0, stream>>>(seq, out);
}